// Round 1
// baseline (81.730 us; speedup 1.0000x reference)
//
#include <hip/hip_runtime.h>
#include <stdint.h>

typedef __attribute__((ext_vector_type(8))) short bf16x8;
typedef __attribute__((ext_vector_type(4))) float f32x4;

static constexpr int B_ROWS = 2097152;
static constexpr int TILES = B_ROWS / 16;            // 131072
static constexpr int BLOCKS = 1024;
static constexpr int WAVES_PER_BLOCK = 4;
static constexpr int TILES_PER_WAVE = TILES / (BLOCKS * WAVES_PER_BLOCK); // 32

__device__ __forceinline__ short f2bf(float f) {
  union { float f; uint32_t u; } v; v.f = f;
  uint32_t r = v.u + 0x7fffu + ((v.u >> 16) & 1u);   // RNE truncate to bf16
  return (short)(r >> 16);
}

__global__ __launch_bounds__(256, 4) void colony_mlp(
    const float* __restrict__ x_local, const float* __restrict__ x_all,
    const float* __restrict__ W1, const float* __restrict__ b1,
    const float* __restrict__ W2, const float* __restrict__ b2,
    const float* __restrict__ W3, const float* __restrict__ b3,
    const float* __restrict__ rw, float* __restrict__ out)
{
  // per-wave private h1 staging: 16 rows x 64 feats, padded stride 72 (b128-aligned, conflict-free)
  __shared__ short h1_lds[WAVES_PER_BLOCK][16 * 72];

  const int tid  = threadIdx.x;
  const int wave = tid >> 6;
  const int lane = tid & 63;
  const int c = lane & 15;   // col / row-in-tile index
  const int g = lane >> 4;   // k-group

  // ---- one-time per-wave setup: weight fragments (k = 8g + j convention) ----
  bf16x8 w1f[4];                       // n-tile t: W1[k][16t+c], K padded 28->32
#pragma unroll
  for (int t = 0; t < 4; ++t)
#pragma unroll
    for (int j = 0; j < 8; ++j) {
      int k = 8 * g + j;
      w1f[t][j] = f2bf(k < 28 ? W1[k * 64 + 16 * t + c] : 0.f);
    }
  bf16x8 w2f[2][2];                    // [n-tile t2][k-step ks]: W2[32ks+8g+j][16t2+c]
#pragma unroll
  for (int t2 = 0; t2 < 2; ++t2)
#pragma unroll
    for (int ks = 0; ks < 2; ++ks)
#pragma unroll
      for (int j = 0; j < 8; ++j) {
        int k = 32 * ks + 8 * g + j;
        w2f[t2][ks][j] = f2bf(W2[k * 32 + 16 * t2 + c]);
      }
  const float w3a = 0.1f * W3[c];      // fold the 0.1 scale into layer 3
  const float w3b = 0.1f * W3[16 + c];
  float b1v[4], b2v[2];
#pragma unroll
  for (int t = 0; t < 4; ++t) b1v[t] = b1[16 * t + c];
#pragma unroll
  for (int t2 = 0; t2 < 2; ++t2) b2v[t2] = b2[16 * t2 + c];

  // softmax(|risk_weights|), uniform
  const float e0 = expf(fabsf(rw[0])), e1 = expf(fabsf(rw[1]));
  const float e2 = expf(fabsf(rw[2])), e3 = expf(fabsf(rw[3]));
  const float inv = 1.f / (e0 + e1 + e2 + e3);
  const float sw0 = e0 * inv, sw1 = e1 * inv, sw2 = e2 * inv, sw3 = e3 * inv;
  const float base = 0.3f + 0.1f * b3[0];

  const int wave_id = blockIdx.x * WAVES_PER_BLOCK + wave;
  const int tile0 = wave_id * TILES_PER_WAVE;
  short* myLds = h1_lds[wave];

  for (int ti = 0; ti < TILES_PER_WAVE; ++ti) {
    const int row_base = (tile0 + ti) * 16;
    const size_t row = (size_t)(row_base + c);

    // ---- A-frag for layer 1: x_flat[k], k = 8g+j ----
    f32x4 fa, fb;
    if (g == 0) {
      fa = *(const f32x4*)(x_local + row * 4);          // k 0..3
      fb = *(const f32x4*)(x_all + row * 28 + 4);       // k 4..7
    } else {
      fa = *(const f32x4*)(x_all + row * 28 + 8 * g);   // k 8g..8g+3
      if (g == 3) { fb = f32x4{0.f, 0.f, 0.f, 0.f}; }   // pad 28..31
      else        { fb = *(const f32x4*)(x_all + row * 28 + 8 * g + 4); }
    }
    bf16x8 af;
    af[0] = f2bf(fa.x); af[1] = f2bf(fa.y); af[2] = f2bf(fa.z); af[3] = f2bf(fa.w);
    af[4] = f2bf(fb.x); af[5] = f2bf(fb.y); af[6] = f2bf(fb.z); af[7] = f2bf(fb.w);

    // ---- layer 1: h1 = relu(x @ W1 + b1), 4 n-tiles ----
    f32x4 acc[4];
#pragma unroll
    for (int t = 0; t < 4; ++t) {
      f32x4 ci = {b1v[t], b1v[t], b1v[t], b1v[t]};
      acc[t] = __builtin_amdgcn_mfma_f32_16x16x32_bf16(af, w1f[t], ci, 0, 0, 0);
    }
    // relu + bf16 + stage to LDS as [row-in-tile][feat]
#pragma unroll
    for (int t = 0; t < 4; ++t)
#pragma unroll
      for (int r = 0; r < 4; ++r) {
        float v = acc[t][r] > 0.f ? acc[t][r] : 0.f;
        myLds[(4 * g + r) * 72 + 16 * t + c] = f2bf(v);
      }
    asm volatile("s_waitcnt lgkmcnt(0)" ::: "memory");  // same-wave RAW fence

    // ---- layer 2: h2 = relu(h1 @ W2 + b2), 2 n-tiles x 2 k-steps ----
    bf16x8 a2_0 = *(const bf16x8*)(myLds + c * 72 + 8 * g);        // feats 8g..8g+7
    bf16x8 a2_1 = *(const bf16x8*)(myLds + c * 72 + 32 + 8 * g);   // feats 32+8g..
    f32x4 acc2[2];
#pragma unroll
    for (int t2 = 0; t2 < 2; ++t2) {
      f32x4 ci = {b2v[t2], b2v[t2], b2v[t2], b2v[t2]};
      ci = __builtin_amdgcn_mfma_f32_16x16x32_bf16(a2_0, w2f[t2][0], ci, 0, 0, 0);
      acc2[t2] = __builtin_amdgcn_mfma_f32_16x16x32_bf16(a2_1, w2f[t2][1], ci, 0, 0, 0);
    }

    // ---- layer 3 + reduce: pr[r] holds 0.1 * h_neural partial for row 4g+r ----
    float pr[4];
#pragma unroll
    for (int r = 0; r < 4; ++r) {
      float h20 = acc2[0][r] > 0.f ? acc2[0][r] : 0.f;
      float h21 = acc2[1][r] > 0.f ? acc2[1][r] : 0.f;
      pr[r] = h20 * w3a + h21 * w3b;
    }
#pragma unroll
    for (int m = 1; m < 16; m <<= 1)
#pragma unroll
      for (int r = 0; r < 4; ++r)
        pr[r] += __shfl_xor(pr[r], m, 64);

    // redistribute: lane l (<16) needs pr[l&3] from group (l>>2)
    float v0 = (lane & 1) ? pr[1] : pr[0];
    float v1 = (lane & 1) ? pr[3] : pr[2];
    float vr = (lane & 2) ? v1 : v0;                    // = pr[lane&3]
    float hn = __shfl(vr, ((lane >> 2) & 3) * 16 + (lane & 3), 64);

    if (lane < 16) {
      const size_t orow = (size_t)(row_base + lane);
      f32x4 xl = *(const f32x4*)(x_local + orow * 4);
      float risk = sw0 * xl.x + sw1 * xl.y + sw2 * xl.z + sw3 * xl.w;
      out[orow] = base - risk + hn;
    }
  }
}

extern "C" void kernel_launch(void* const* d_in, const int* in_sizes, int n_in,
                              void* d_out, int out_size, void* d_ws, size_t ws_size,
                              hipStream_t stream) {
  colony_mlp<<<dim3(BLOCKS), dim3(256), 0, stream>>>(
      (const float*)d_in[0], (const float*)d_in[1], (const float*)d_in[2],
      (const float*)d_in[3], (const float*)d_in[4], (const float*)d_in[5],
      (const float*)d_in[6], (const float*)d_in[7], (const float*)d_in[8],
      (float*)d_out);
}

// Round 2
// 51.911 us; speedup vs baseline: 1.5744x; 1.5744x over previous
//
#include <hip/hip_runtime.h>
#include <hip/hip_bf16.h>
#include <stdint.h>

typedef __attribute__((ext_vector_type(8))) short bf16x8;
typedef __attribute__((ext_vector_type(4))) float f32x4;

static constexpr int B_ROWS = 2097152;
static constexpr int TILES = B_ROWS / 16;            // 131072
static constexpr int BLOCKS = 1024;
static constexpr int WAVES_PER_BLOCK = 4;
static constexpr int TILES_PER_WAVE = TILES / (BLOCKS * WAVES_PER_BLOCK); // 32

__device__ __forceinline__ short f2bf(float f) {
  union { float f; uint32_t u; } v; v.f = f;
  uint32_t r = v.u + 0x7fffu + ((v.u >> 16) & 1u);   // RNE truncate to bf16
  return (short)(r >> 16);
}
__device__ __forceinline__ uint32_t pk2(float lo, float hi) {
  union { __hip_bfloat162 h; uint32_t u; } v;
  v.h = __float22bfloat162_rn(float2{lo, hi});       // v_cvt_pk_bf16_f32
  return v.u;
}
__device__ __forceinline__ float relu(float x) { return x > 0.f ? x : 0.f; }

// Operand-swapped MLP: layer outputs carry feat on (g,r), batch-row on c.
// No LDS, no transpose; layer-2 A-frag is an in-lane repack with the k-perm
//   feat(g,j,ks) = 16*(2*ks + (j>>2)) + 4*g + (j&3)
// baked into the W2 fragment at setup. b1 folded into k=28 slot (x padded w/ 1.0).
__global__ __launch_bounds__(256, 4) void colony_mlp(
    const float* __restrict__ x_local, const float* __restrict__ x_all,
    const float* __restrict__ W1, const float* __restrict__ b1,
    const float* __restrict__ W2, const float* __restrict__ b2,
    const float* __restrict__ W3, const float* __restrict__ b3,
    const float* __restrict__ rw, float* __restrict__ out)
{
  const int tid  = threadIdx.x;
  const int wave = tid >> 6;
  const int lane = tid & 63;
  const int c = lane & 15;   // batch-row-in-tile (and weight-fragment col)
  const int g = lane >> 4;   // k-group

  // ---- W1^T fragments (A-operand): w1f[t][j] = W1[k=8g+j][16t+c] ----
  // k=28 slot (g==3,j==4) carries b1; k=29..31 are zero.
  bf16x8 w1f[4];
#pragma unroll
  for (int t = 0; t < 4; ++t)
#pragma unroll
    for (int j = 0; j < 8; ++j) {
      int k = 8 * g + j;
      float v = (k < 28) ? W1[k * 64 + 16 * t + c]
              : (k == 28) ? b1[16 * t + c] : 0.f;
      w1f[t][j] = f2bf(v);
    }
  // ---- W2^T fragments with the layer-2 k-perm ----
  bf16x8 w2f[2][2];   // [t2][ks]
#pragma unroll
  for (int t2 = 0; t2 < 2; ++t2)
#pragma unroll
    for (int ks = 0; ks < 2; ++ks)
#pragma unroll
      for (int j = 0; j < 8; ++j) {
        int feat = 16 * (2 * ks + (j >> 2)) + 4 * g + (j & 3);
        w2f[t2][ks][j] = f2bf(W2[feat * 32 + 16 * t2 + c]);
      }
  // per-(g,r) layer-2 bias and layer-3 weights (feat2 = 16t2 + 4g + r)
  float b2v[2][4], w3v[2][4];
#pragma unroll
  for (int t2 = 0; t2 < 2; ++t2)
#pragma unroll
    for (int r = 0; r < 4; ++r) {
      b2v[t2][r] = b2[16 * t2 + 4 * g + r];
      w3v[t2][r] = 0.1f * W3[16 * t2 + 4 * g + r];
    }

  // softmax(|risk_weights|), uniform
  const float e0 = expf(fabsf(rw[0])), e1 = expf(fabsf(rw[1]));
  const float e2 = expf(fabsf(rw[2])), e3 = expf(fabsf(rw[3]));
  const float inv = 1.f / (e0 + e1 + e2 + e3);
  const float sw0 = e0 * inv, sw1 = e1 * inv, sw2 = e2 * inv, sw3 = e3 * inv;
  const float base = 0.3f + 0.1f * b3[0];

  const int wave_id = blockIdx.x * WAVES_PER_BLOCK + wave;
  const int tile0 = wave_id * TILES_PER_WAVE;
  const int row0 = tile0 * 16 + c;

  // per-lane strided load pointers (uniform control flow; g==3's fb is a
  // discarded dup — its weight slots are 0 / the 1.0-bias slot overrides)
  const float* pa; ptrdiff_t stA;
  if (g == 0) { pa = x_local + (size_t)row0 * 4;          stA = 16 * 4;  }
  else        { pa = x_all  + (size_t)row0 * 28 + 8 * g;  stA = 16 * 28; }
  const int fboff = (g == 0) ? 4 : (g == 3) ? 16 : 8 * g + 4;
  const float* pb = x_all + (size_t)row0 * 28 + fboff;
  const ptrdiff_t stB = 16 * 28;

  f32x4 ca = *(const f32x4*)pa;
  f32x4 cb = *(const f32x4*)pb;

  for (int ti = 0; ti < TILES_PER_WAVE; ++ti) {
    // ---- prefetch next tile (depth 1); last iter re-reads in-bounds ----
    if (ti + 1 < TILES_PER_WAVE) { pa += stA; pb += stB; }
    f32x4 na = *(const f32x4*)pa;
    f32x4 nb = *(const f32x4*)pb;

    // ---- B-operand for layer 1: x_flat[row=c][k=8g+j], k=28 slot = 1.0 ----
    bf16x8 af;
    uint32_t* au = (uint32_t*)&af;
    au[0] = pk2(ca.x, ca.y);
    au[1] = pk2(ca.z, ca.w);
    au[2] = (g == 3) ? 0x00003F80u : pk2(cb.x, cb.y);   // bf16(1.0) in slot j=4
    au[3] = pk2(cb.z, cb.w);

    // ---- layer 1 (swapped): acc[t][r] = h1[row=c][feat=16t+4g+r] (bias incl.) ----
    f32x4 acc[4];
#pragma unroll
    for (int t = 0; t < 4; ++t) {
      f32x4 zero = {0.f, 0.f, 0.f, 0.f};
      acc[t] = __builtin_amdgcn_mfma_f32_16x16x32_bf16(w1f[t], af, zero, 0, 0, 0);
    }

    // ---- in-lane repack: a2[ks][j] = relu(h1[row=c][feat(g,j,ks)]) ----
    bf16x8 a2[2];
#pragma unroll
    for (int ks = 0; ks < 2; ++ks) {
      uint32_t* u = (uint32_t*)&a2[ks];
      u[0] = pk2(relu(acc[2 * ks + 0][0]), relu(acc[2 * ks + 0][1]));
      u[1] = pk2(relu(acc[2 * ks + 0][2]), relu(acc[2 * ks + 0][3]));
      u[2] = pk2(relu(acc[2 * ks + 1][0]), relu(acc[2 * ks + 1][1]));
      u[3] = pk2(relu(acc[2 * ks + 1][2]), relu(acc[2 * ks + 1][3]));
    }

    // ---- layer 2 (swapped): acc2[t2][r] = h2[row=c][feat2=16t2+4g+r] ----
    f32x4 acc2[2];
#pragma unroll
    for (int t2 = 0; t2 < 2; ++t2) {
      f32x4 ci = {b2v[t2][0], b2v[t2][1], b2v[t2][2], b2v[t2][3]};
      ci = __builtin_amdgcn_mfma_f32_16x16x32_bf16(w2f[t2][0], a2[0], ci, 0, 0, 0);
      acc2[t2] = __builtin_amdgcn_mfma_f32_16x16x32_bf16(w2f[t2][1], a2[1], ci, 0, 0, 0);
    }

    // ---- layer 3: in-lane partial, then reduce over g (2 shfl) ----
    float p = 0.f;
#pragma unroll
    for (int t2 = 0; t2 < 2; ++t2)
#pragma unroll
      for (int r = 0; r < 4; ++r)
        p = fmaf(relu(acc2[t2][r]), w3v[t2][r], p);
    p += __shfl_xor(p, 16, 64);
    p += __shfl_xor(p, 32, 64);

    // ---- epilogue: g==0 lanes hold x_local for their row in ca ----
    if (lane < 16) {
      float risk = sw0 * ca.x + sw1 * ca.y + sw2 * ca.z + sw3 * ca.w;
      out[(size_t)(tile0 + ti) * 16 + lane] = base - risk + p;
    }

    ca = na; cb = nb;
  }
}

extern "C" void kernel_launch(void* const* d_in, const int* in_sizes, int n_in,
                              void* d_out, int out_size, void* d_ws, size_t ws_size,
                              hipStream_t stream) {
  colony_mlp<<<dim3(BLOCKS), dim3(256), 0, stream>>>(
      (const float*)d_in[0], (const float*)d_in[1], (const float*)d_in[2],
      (const float*)d_in[3], (const float*)d_in[4], (const float*)d_in[5],
      (const float*)d_in[6], (const float*)d_in[7], (const float*)d_in[8],
      (float*)d_out);
}

// Round 3
// 51.168 us; speedup vs baseline: 1.5973x; 1.0145x over previous
//
#include <hip/hip_runtime.h>
#include <hip/hip_bf16.h>
#include <stdint.h>

typedef __attribute__((ext_vector_type(8))) short bf16x8;
typedef __attribute__((ext_vector_type(4))) float f32x4;

static constexpr int B_ROWS = 2097152;
static constexpr int TILES = B_ROWS / 16;            // 131072
static constexpr int BLOCKS = 1024;
static constexpr int WAVES_PER_BLOCK = 4;
static constexpr int TILES_PER_WAVE = TILES / (BLOCKS * WAVES_PER_BLOCK); // 32

__device__ __forceinline__ short f2bf(float f) {
  union { float f; uint32_t u; } v; v.f = f;
  uint32_t r = v.u + 0x7fffu + ((v.u >> 16) & 1u);   // RNE truncate to bf16
  return (short)(r >> 16);
}
__device__ __forceinline__ uint32_t pk2(float lo, float hi) {
  union { __hip_bfloat162 h; uint32_t u; } v;
  v.h = __float22bfloat162_rn(float2{lo, hi});       // v_cvt_pk_bf16_f32
  return v.u;
}
__device__ __forceinline__ float relu(float x) { return x > 0.f ? x : 0.f; }

// Operand-swapped MLP (batch-row on c, feat on (g,r)); no LDS, no transpose.
// R3: depth-2 prefetch via 2x-unrolled main loop (static reg names).
__global__ __launch_bounds__(256, 4) void colony_mlp(
    const float* __restrict__ x_local, const float* __restrict__ x_all,
    const float* __restrict__ W1, const float* __restrict__ b1,
    const float* __restrict__ W2, const float* __restrict__ b2,
    const float* __restrict__ W3, const float* __restrict__ b3,
    const float* __restrict__ rw, float* __restrict__ out)
{
  const int tid  = threadIdx.x;
  const int wave = tid >> 6;
  const int lane = tid & 63;
  const int c = lane & 15;   // batch-row-in-tile (and weight-fragment col)
  const int g = lane >> 4;   // k-group

  // ---- W1^T fragments (A-operand): w1f[t][j] = W1[k=8g+j][16t+c] ----
  // k=28 slot (g==3,j==4) carries b1; k=29..31 are zero.
  bf16x8 w1f[4];
#pragma unroll
  for (int t = 0; t < 4; ++t)
#pragma unroll
    for (int j = 0; j < 8; ++j) {
      int k = 8 * g + j;
      float v = (k < 28) ? W1[k * 64 + 16 * t + c]
              : (k == 28) ? b1[16 * t + c] : 0.f;
      w1f[t][j] = f2bf(v);
    }
  // ---- W2^T fragments with the layer-2 k-perm: feat = 16*(2ks+(j>>2)) + 4g + (j&3) ----
  bf16x8 w2f[2][2];   // [t2][ks]
#pragma unroll
  for (int t2 = 0; t2 < 2; ++t2)
#pragma unroll
    for (int ks = 0; ks < 2; ++ks)
#pragma unroll
      for (int j = 0; j < 8; ++j) {
        int feat = 16 * (2 * ks + (j >> 2)) + 4 * g + (j & 3);
        w2f[t2][ks][j] = f2bf(W2[feat * 32 + 16 * t2 + c]);
      }
  // per-(g,r) layer-2 bias and layer-3 weights (feat2 = 16t2 + 4g + r)
  float b2v[2][4], w3v[2][4];
#pragma unroll
  for (int t2 = 0; t2 < 2; ++t2)
#pragma unroll
    for (int r = 0; r < 4; ++r) {
      b2v[t2][r] = b2[16 * t2 + 4 * g + r];
      w3v[t2][r] = 0.1f * W3[16 * t2 + 4 * g + r];
    }

  // softmax(|risk_weights|), uniform
  const float e0 = expf(fabsf(rw[0])), e1 = expf(fabsf(rw[1]));
  const float e2 = expf(fabsf(rw[2])), e3 = expf(fabsf(rw[3]));
  const float inv = 1.f / (e0 + e1 + e2 + e3);
  const float sw0 = e0 * inv, sw1 = e1 * inv, sw2 = e2 * inv, sw3 = e3 * inv;
  const float base = 0.3f + 0.1f * b3[0];

  const int wave_id = blockIdx.x * WAVES_PER_BLOCK + wave;
  const int tile0 = wave_id * TILES_PER_WAVE;
  const int row0 = tile0 * 16 + c;

  // two interleaved tile streams (even / odd), each advancing 2 tiles
  const float* paE; const float* paO; ptrdiff_t stA;
  if (g == 0) { paE = x_local + (size_t)row0 * 4;          stA = 16 * 4;  }
  else        { paE = x_all  + (size_t)row0 * 28 + 8 * g;  stA = 16 * 28; }
  const int fboff = (g == 0) ? 4 : (g == 3) ? 16 : 8 * g + 4;
  const float* pbE = x_all + (size_t)row0 * 28 + fboff;
  const ptrdiff_t stB = 16 * 28;
  paO = paE + stA;
  const float* pbO = pbE + stB;

  f32x4 ca0 = *(const f32x4*)paE, cb0 = *(const f32x4*)pbE;  // tile ti
  f32x4 ca1 = *(const f32x4*)paO, cb1 = *(const f32x4*)pbO;  // tile ti+1

  auto compute = [&](const f32x4& ca, const f32x4& cb, int tidx) {
    // B-operand layer 1: x_flat[row=c][k=8g+j], k=28 slot = 1.0 (bias)
    bf16x8 af;
    uint32_t* au = (uint32_t*)&af;
    au[0] = pk2(ca.x, ca.y);
    au[1] = pk2(ca.z, ca.w);
    au[2] = (g == 3) ? 0x00003F80u : pk2(cb.x, cb.y);
    au[3] = pk2(cb.z, cb.w);

    f32x4 acc[4];
#pragma unroll
    for (int t = 0; t < 4; ++t) {
      f32x4 zero = {0.f, 0.f, 0.f, 0.f};
      acc[t] = __builtin_amdgcn_mfma_f32_16x16x32_bf16(w1f[t], af, zero, 0, 0, 0);
    }
    // in-lane repack: a2[ks][j] = relu(h1[row=c][feat(g,j,ks)])
    bf16x8 a2[2];
#pragma unroll
    for (int ks = 0; ks < 2; ++ks) {
      uint32_t* u = (uint32_t*)&a2[ks];
      u[0] = pk2(relu(acc[2 * ks + 0][0]), relu(acc[2 * ks + 0][1]));
      u[1] = pk2(relu(acc[2 * ks + 0][2]), relu(acc[2 * ks + 0][3]));
      u[2] = pk2(relu(acc[2 * ks + 1][0]), relu(acc[2 * ks + 1][1]));
      u[3] = pk2(relu(acc[2 * ks + 1][2]), relu(acc[2 * ks + 1][3]));
    }
    f32x4 acc2[2];
#pragma unroll
    for (int t2 = 0; t2 < 2; ++t2) {
      f32x4 ci = {b2v[t2][0], b2v[t2][1], b2v[t2][2], b2v[t2][3]};
      ci = __builtin_amdgcn_mfma_f32_16x16x32_bf16(w2f[t2][0], a2[0], ci, 0, 0, 0);
      acc2[t2] = __builtin_amdgcn_mfma_f32_16x16x32_bf16(w2f[t2][1], a2[1], ci, 0, 0, 0);
    }
    float p = 0.f;
#pragma unroll
    for (int t2 = 0; t2 < 2; ++t2)
#pragma unroll
      for (int r = 0; r < 4; ++r)
        p = fmaf(relu(acc2[t2][r]), w3v[t2][r], p);
    p += __shfl_xor(p, 16, 64);
    p += __shfl_xor(p, 32, 64);

    if (lane < 16) {
      float risk = sw0 * ca.x + sw1 * ca.y + sw2 * ca.z + sw3 * ca.w;
      out[(size_t)(tile0 + tidx) * 16 + lane] = base - risk + p;
    }
  };

  for (int ti = 0; ti < TILES_PER_WAVE; ti += 2) {
    // issue prefetch for tiles ti+2, ti+3 first (4 independent loads in flight)
    if (ti + 2 < TILES_PER_WAVE) { paE += 2 * stA; pbE += 2 * stB; }
    f32x4 na0 = *(const f32x4*)paE;
    f32x4 nb0 = *(const f32x4*)pbE;
    if (ti + 3 < TILES_PER_WAVE) { paO += 2 * stA; pbO += 2 * stB; }
    f32x4 na1 = *(const f32x4*)paO;
    f32x4 nb1 = *(const f32x4*)pbO;

    compute(ca0, cb0, ti);
    compute(ca1, cb1, ti + 1);

    ca0 = na0; cb0 = nb0; ca1 = na1; cb1 = nb1;
  }
}

extern "C" void kernel_launch(void* const* d_in, const int* in_sizes, int n_in,
                              void* d_out, int out_size, void* d_ws, size_t ws_size,
                              hipStream_t stream) {
  colony_mlp<<<dim3(BLOCKS), dim3(256), 0, stream>>>(
      (const float*)d_in[0], (const float*)d_in[1], (const float*)d_in[2],
      (const float*)d_in[3], (const float*)d_in[4], (const float*)d_in[5],
      (const float*)d_in[6], (const float*)d_in[7], (const float*)d_in[8],
      (float*)d_out);
}

// Round 4
// 50.763 us; speedup vs baseline: 1.6100x; 1.0080x over previous
//
#include <hip/hip_runtime.h>
#include <hip/hip_bf16.h>
#include <stdint.h>

typedef __attribute__((ext_vector_type(8))) short bf16x8;
typedef __attribute__((ext_vector_type(4))) float f32x4;

static constexpr int B_ROWS = 2097152;
static constexpr int TILES = B_ROWS / 16;            // 131072
static constexpr int BLOCKS = 1024;
static constexpr int WAVES_PER_BLOCK = 4;
static constexpr int TOTAL_WAVES = BLOCKS * WAVES_PER_BLOCK;       // 4096
static constexpr int ITERS = TILES / TOTAL_WAVES;                  // 32

__device__ __forceinline__ short f2bf(float f) {
  union { float f; uint32_t u; } v; v.f = f;
  uint32_t r = v.u + 0x7fffu + ((v.u >> 16) & 1u);   // RNE truncate to bf16
  return (short)(r >> 16);
}
__device__ __forceinline__ uint32_t pk2(float lo, float hi) {
  union { __hip_bfloat162 h; uint32_t u; } v;
  v.h = __float22bfloat162_rn(float2{lo, hi});       // v_cvt_pk_bf16_f32
  return v.u;
}
__device__ __forceinline__ float relu(float x) { return x > 0.f ? x : 0.f; }

// Operand-swapped MLP (batch-row on c, feat on (g,r)); no LDS, no transpose.
// R4: grid-stride tile interleave (tile = wave_id + it*4096) so all in-flight
// waves form one dense marching front (DRAM row-buffer friendly), replacing
// 4096 independent 57KB streams.
__global__ __launch_bounds__(256, 4) void colony_mlp(
    const float* __restrict__ x_local, const float* __restrict__ x_all,
    const float* __restrict__ W1, const float* __restrict__ b1,
    const float* __restrict__ W2, const float* __restrict__ b2,
    const float* __restrict__ W3, const float* __restrict__ b3,
    const float* __restrict__ rw, float* __restrict__ out)
{
  const int tid  = threadIdx.x;
  const int wave = tid >> 6;
  const int lane = tid & 63;
  const int c = lane & 15;   // batch-row-in-tile (and weight-fragment col)
  const int g = lane >> 4;   // k-group

  // ---- W1^T fragments (A-operand): w1f[t][j] = W1[k=8g+j][16t+c] ----
  // k=28 slot (g==3,j==4) carries b1; k=29..31 are zero.
  bf16x8 w1f[4];
#pragma unroll
  for (int t = 0; t < 4; ++t)
#pragma unroll
    for (int j = 0; j < 8; ++j) {
      int k = 8 * g + j;
      float v = (k < 28) ? W1[k * 64 + 16 * t + c]
              : (k == 28) ? b1[16 * t + c] : 0.f;
      w1f[t][j] = f2bf(v);
    }
  // ---- W2^T fragments with the layer-2 k-perm: feat = 16*(2ks+(j>>2)) + 4g + (j&3) ----
  bf16x8 w2f[2][2];   // [t2][ks]
#pragma unroll
  for (int t2 = 0; t2 < 2; ++t2)
#pragma unroll
    for (int ks = 0; ks < 2; ++ks)
#pragma unroll
      for (int j = 0; j < 8; ++j) {
        int feat = 16 * (2 * ks + (j >> 2)) + 4 * g + (j & 3);
        w2f[t2][ks][j] = f2bf(W2[feat * 32 + 16 * t2 + c]);
      }
  // per-(g,r) layer-2 bias and layer-3 weights (feat2 = 16t2 + 4g + r)
  float b2v[2][4], w3v[2][4];
#pragma unroll
  for (int t2 = 0; t2 < 2; ++t2)
#pragma unroll
    for (int r = 0; r < 4; ++r) {
      b2v[t2][r] = b2[16 * t2 + 4 * g + r];
      w3v[t2][r] = 0.1f * W3[16 * t2 + 4 * g + r];
    }

  // softmax(|risk_weights|), uniform
  const float e0 = expf(fabsf(rw[0])), e1 = expf(fabsf(rw[1]));
  const float e2 = expf(fabsf(rw[2])), e3 = expf(fabsf(rw[3]));
  const float inv = 1.f / (e0 + e1 + e2 + e3);
  const float sw0 = e0 * inv, sw1 = e1 * inv, sw2 = e2 * inv, sw3 = e3 * inv;
  const float base = 0.3f + 0.1f * b3[0];

  const int wave_id = blockIdx.x * WAVES_PER_BLOCK + wave;   // 0..4095

  // even/odd iteration streams; tiles: even = wave_id + it*4096 (it even),
  // odd = wave_id + it*4096 (it odd). Each stream advances 2*4096 tiles.
  const size_t rowE = (size_t)wave_id * 16 + c;
  const size_t rowO = (size_t)(wave_id + TOTAL_WAVES) * 16 + c;

  const float* paE; const float* paO; ptrdiff_t stA;
  if (g == 0) {
    paE = x_local + rowE * 4;  paO = x_local + rowO * 4;
    stA = (ptrdiff_t)2 * TOTAL_WAVES * 16 * 4;
  } else {
    paE = x_all + rowE * 28 + 8 * g;  paO = x_all + rowO * 28 + 8 * g;
    stA = (ptrdiff_t)2 * TOTAL_WAVES * 16 * 28;
  }
  const int fboff = (g == 0) ? 4 : (g == 3) ? 16 : 8 * g + 4;
  const float* pbE = x_all + rowE * 28 + fboff;
  const float* pbO = x_all + rowO * 28 + fboff;
  const ptrdiff_t stB = (ptrdiff_t)2 * TOTAL_WAVES * 16 * 28;

  f32x4 ca0 = *(const f32x4*)paE, cb0 = *(const f32x4*)pbE;  // iter it
  f32x4 ca1 = *(const f32x4*)paO, cb1 = *(const f32x4*)pbO;  // iter it+1

  auto compute = [&](const f32x4& ca, const f32x4& cb, int tile) {
    // B-operand layer 1: x_flat[row=c][k=8g+j], k=28 slot = 1.0 (bias)
    bf16x8 af;
    uint32_t* au = (uint32_t*)&af;
    au[0] = pk2(ca.x, ca.y);
    au[1] = pk2(ca.z, ca.w);
    au[2] = (g == 3) ? 0x00003F80u : pk2(cb.x, cb.y);
    au[3] = pk2(cb.z, cb.w);

    f32x4 acc[4];
#pragma unroll
    for (int t = 0; t < 4; ++t) {
      f32x4 zero = {0.f, 0.f, 0.f, 0.f};
      acc[t] = __builtin_amdgcn_mfma_f32_16x16x32_bf16(w1f[t], af, zero, 0, 0, 0);
    }
    // in-lane repack: a2[ks][j] = relu(h1[row=c][feat(g,j,ks)])
    bf16x8 a2[2];
#pragma unroll
    for (int ks = 0; ks < 2; ++ks) {
      uint32_t* u = (uint32_t*)&a2[ks];
      u[0] = pk2(relu(acc[2 * ks + 0][0]), relu(acc[2 * ks + 0][1]));
      u[1] = pk2(relu(acc[2 * ks + 0][2]), relu(acc[2 * ks + 0][3]));
      u[2] = pk2(relu(acc[2 * ks + 1][0]), relu(acc[2 * ks + 1][1]));
      u[3] = pk2(relu(acc[2 * ks + 1][2]), relu(acc[2 * ks + 1][3]));
    }
    f32x4 acc2[2];
#pragma unroll
    for (int t2 = 0; t2 < 2; ++t2) {
      f32x4 ci = {b2v[t2][0], b2v[t2][1], b2v[t2][2], b2v[t2][3]};
      ci = __builtin_amdgcn_mfma_f32_16x16x32_bf16(w2f[t2][0], a2[0], ci, 0, 0, 0);
      acc2[t2] = __builtin_amdgcn_mfma_f32_16x16x32_bf16(w2f[t2][1], a2[1], ci, 0, 0, 0);
    }
    float p = 0.f;
#pragma unroll
    for (int t2 = 0; t2 < 2; ++t2)
#pragma unroll
      for (int r = 0; r < 4; ++r)
        p = fmaf(relu(acc2[t2][r]), w3v[t2][r], p);
    p += __shfl_xor(p, 16, 64);
    p += __shfl_xor(p, 32, 64);

    if (lane < 16) {
      float risk = sw0 * ca.x + sw1 * ca.y + sw2 * ca.z + sw3 * ca.w;
      out[(size_t)tile * 16 + lane] = base - risk + p;
    }
  };

  for (int it = 0; it < ITERS; it += 2) {
    // issue prefetch for iterations it+2, it+3 first (4 independent loads)
    if (it + 2 < ITERS) { paE += stA; pbE += stB; }
    f32x4 na0 = *(const f32x4*)paE;
    f32x4 nb0 = *(const f32x4*)pbE;
    if (it + 3 < ITERS) { paO += stA; pbO += stB; }
    f32x4 na1 = *(const f32x4*)paO;
    f32x4 nb1 = *(const f32x4*)pbO;

    compute(ca0, cb0, wave_id + it * TOTAL_WAVES);
    compute(ca1, cb1, wave_id + (it + 1) * TOTAL_WAVES);

    ca0 = na0; cb0 = nb0; ca1 = na1; cb1 = nb1;
  }
}

extern "C" void kernel_launch(void* const* d_in, const int* in_sizes, int n_in,
                              void* d_out, int out_size, void* d_ws, size_t ws_size,
                              hipStream_t stream) {
  colony_mlp<<<dim3(BLOCKS), dim3(256), 0, stream>>>(
      (const float*)d_in[0], (const float*)d_in[1], (const float*)d_in[2],
      (const float*)d_in[3], (const float*)d_in[4], (const float*)d_in[5],
      (const float*)d_in[6], (const float*)d_in[7], (const float*)d_in[8],
      (float*)d_out);
}